// Round 20
// baseline (49.565 us; speedup 1.0000x reference)
//
#include <hip/hip_runtime.h>

typedef __attribute__((ext_vector_type(4))) float f4;
typedef __attribute__((ext_vector_type(8))) short bf8;     // 8 x bf16 bits
typedef __attribute__((ext_vector_type(4))) float f32x4;
typedef __attribute__((ext_vector_type(2))) unsigned int u32x2;
typedef __attribute__((ext_vector_type(4))) unsigned int u32x4;

__device__ __forceinline__ float silu_f(float v) {
    return v * __builtin_amdgcn_rcpf(1.0f + __expf(-v));
}
__device__ __forceinline__ ushort f2bf(float f) {   // RNE f32->bf16 (setup only)
    unsigned u = __float_as_uint(f);
    u += 0x7fff + ((u >> 16) & 1);
    return (ushort)(u >> 16);
}
__device__ __forceinline__ unsigned cvtpk(float lo, float hi) {
    unsigned r;
    asm("v_cvt_pk_bf16_f32 %0, %1, %2" : "=v"(r) : "v"(lo), "v"(hi));
    return r;   // D[15:0]=bf16(lo), D[31:16]=bf16(hi)
}
// 8 bf16 (u32x4) -> two f4
__device__ __forceinline__ void cvt8(u32x4 v, f4& lo, f4& hi) {
    lo[0] = __uint_as_float(v[0] << 16);
    lo[1] = __uint_as_float(v[0] & 0xffff0000u);
    lo[2] = __uint_as_float(v[1] << 16);
    lo[3] = __uint_as_float(v[1] & 0xffff0000u);
    hi[0] = __uint_as_float(v[2] << 16);
    hi[1] = __uint_as_float(v[2] & 0xffff0000u);
    hi[2] = __uint_as_float(v[3] << 16);
    hi[3] = __uint_as_float(v[3] & 0xffff0000u);
}

// fused: blocks 0..95   -> z_l = silu(emb1 @ Wz[l] + bz[l])
//        blocks 96..127 -> WT  [l][n][k] = bf16(Wm[l][k][n])   (k_main weights)
//        blocks 128..175-> WefT[l][n][kk] = bf16(Wef[l][kk][n]) (k_e weights)
extern "C" __global__ void k_zw(const float* __restrict__ emb1,
                                const float* __restrict__ Wz,
                                const float* __restrict__ bz,
                                const float* __restrict__ Wm,
                                const float* __restrict__ Wef,
                                float* __restrict__ z,
                                ushort* __restrict__ WT,
                                ushort* __restrict__ WefT) {
    if (blockIdx.x < 96) {
        int tid = blockIdx.x * 256 + threadIdx.x;   // 24576
        int k = tid & 63;
        int n = (tid >> 6) & 63;
        int b = (tid >> 12) & 1;
        int l = tid >> 13;
        const float* er = emb1 + (b * 64 + n) * 128;
        const float* w  = Wz + l * 8192 + k;
        float acc = bz[l * 64 + k];
        #pragma unroll 8
        for (int c = 0; c < 128; ++c) acc = fmaf(er[c], w[c * 64], acc);
        z[tid] = silu_f(acc);
    } else if (blockIdx.x < 128) {
        int tid = (blockIdx.x - 96) * 256 + threadIdx.x;  // 8192
        int l = tid >> 12, n = (tid >> 6) & 63, k = tid & 63;
        WT[tid] = f2bf(Wm[l * 4096 + k * 64 + n]);
    } else {
        int tid = (blockIdx.x - 128) * 256 + threadIdx.x; // 12288
        int l = tid >> 12, n = (tid >> 6) & 63, k = tid & 63;
        WefT[tid] = f2bf(Wef[l * 4096 + k * 64 + n]);
    }
}

// e'_l = (ef @ Wef[l]) * z-factor via MFMA (R19-validated, unchanged).
extern "C" __global__ void __launch_bounds__(64)
k_e(const float* __restrict__ ef, const ushort* __restrict__ WefT,
    const float* __restrict__ z, ushort* __restrict__ e) {
    __shared__ ushort EF[2048];   // 16 rows x 64 bf16, 128B rows, XOR-swizzled

    const int t   = threadIdx.x;      // 64
    const int blk = blockIdx.x;       // 1536
    const int l    = blk >> 9;
    const int rt16 = blk & 511;
    const int r0g  = rt16 * 16;       // first global ef-row of this wave

    const int rl = t >> 2;
    const int c0 = (t & 3) << 4;
    {
        const float* src = ef + (size_t)(r0g + rl) * 64 + c0;
        unsigned xw[8];
        #pragma unroll
        for (int q = 0; q < 4; ++q) {
            f4 v = *(const f4*)(src + 4 * q);
            xw[2 * q]     = cvtpk(v[0], v[1]);
            xw[2 * q + 1] = cvtpk(v[2], v[3]);
        }
        char* rowp = (char*)EF + rl * 128;
        const int rx = (rl & 7) << 4;
        u32x4 vlo = {xw[0], xw[1], xw[2], xw[3]};
        u32x4 vhi = {xw[4], xw[5], xw[6], xw[7]};
        *(u32x4*)(rowp + ((c0 * 2)      ^ rx)) = vlo;
        *(u32x4*)(rowp + ((c0 * 2 + 16) ^ rx)) = vhi;
    }
    // wave-local LDS: program order + lgkmcnt suffices, no barrier

    const int lr = t & 15, lg = t >> 4;
    const int abyte = lr * 128;
    const int arx   = (lr & 7) << 4;
    bf8 a0 = *(const bf8*)((const char*)EF + abyte + ((     lg * 16) ^ arx));
    bf8 a1 = *(const bf8*)((const char*)EF + abyte + ((64 + lg * 16) ^ arx));

    const int b  = r0g >> 12;
    const int fi = (r0g >> 6) & 63;
    const int se = (r0g & 63) + lr;
    const int mn = (l == 1) ? fi : se;
    const float* zb = z + l * 8192 + b * 4096 + mn * 64;
    ushort* erow = e + (size_t)l * 524288 + (size_t)(r0g + lr) * 64;

    #pragma unroll
    for (int nt = 0; nt < 4; ++nt) {
        const ushort* wp = WefT + l * 4096 + (nt * 16 + lr) * 64 + lg * 8;
        bf8 b0 = *(const bf8*)(wp);
        bf8 b1 = *(const bf8*)(wp + 32);
        f32x4 acc = {0.f, 0.f, 0.f, 0.f};
        acc = __builtin_amdgcn_mfma_f32_16x16x32_bf16(b0, a0, acc, 0, 0, 0);
        acc = __builtin_amdgcn_mfma_f32_16x16x32_bf16(b1, a1, acc, 0, 0, 0);
        const int k0 = nt * 16 + lg * 4;
        f4 zf = *(const f4*)(zb + k0);
        u32x2 pk = {cvtpk(acc[0] * zf[0], acc[1] * zf[1]),
                    cvtpk(acc[2] * zf[2], acc[3] * zf[3])};
        *(u32x2*)(erow + k0) = pk;
    }
}

// R16/R19 k_main with ONE change: phase D uses R1's store geometry —
// per wave-instruction 4 rows x 256B CONTIGUOUS (16 lanes/row), instead of
// 8 rows x 128B. Theory: HBM/L2 write granularity is 256B; 128B-per-row
// coverage triggers read-modify-write => the persistent 1.59x WRITE_SIZE
// amplification (R6: 208MB WITH full-128B-line stores; R1: exactly 131MB
// with 256B-per-row coverage).
extern "C" __global__ void __launch_bounds__(256, 4)
k_main(const ushort* __restrict__ e, const float* __restrict__ table,
       const ushort* __restrict__ WT, const float* __restrict__ bm,
       float* __restrict__ out) {
    __shared__ ushort Wl[8192];       // both layers, 128B rows, XOR-swizzled
    __shared__ ushort XH[8192];       // [0,8K): X rows; [8K,16K): H rows.
                                      // O-buffer (f32) overlays wave's own
                                      // X slice (rows 0-7) + H slice (8-15).

    const int t   = threadIdx.x;
    // XCD-chunked, reuse-tight decode (2048 blocks, 8 XCDs; pure bijection)
    const int raw = blockIdx.x;
    const int sem = (raw & 7) * 256 + (raw >> 3);
    const int ig  = sem >> 8;
    const int pos = sem & 255;
    const int b   = pos >> 7;
    const int jq  = (pos >> 3) & 15;
    const int i   = ig * 8 + (pos & 7);
    const int j0  = jq * 4;

    // stage both weight layers swizzled into LDS (once per block)
    #pragma unroll
    for (int p = 0; p < 4; ++p) {
        int g   = p * 256 + t;                  // 1024 x 16B chunks
        int row = g >> 3;                       // 128 rows x 128B
        int cb  = (g & 7) * 16;
        u32x4 v = *(const u32x4*)(WT + g * 8);
        *(u32x4*)((char*)Wl + row * 128 + (cb ^ ((row & 7) << 4))) = v;
    }

    // build-role ids (coalesced: thread covers 16 cols of one row)
    const int r  = t >> 2;
    const int c0 = (t & 3) << 4;
    // frag-role ids
    const int ln = t & 63, w = t >> 6;
    const int lr = ln & 15, lg = ln >> 4;
    const int abyte = (w * 16 + lr) * 128;
    const int arx   = (lr & 7) << 4;
    // output-transpose ids: 4 row-groups x 16 chunks (256B/row per instr)
    const int orr = ln >> 4, os = ln & 15;
    const int obrow = ((lr & 8) ? (8192 + w * 2048) : (w * 2048)) + (lr & 7) * 256;

    // e1 slice: bf16 load once; fold f32*pat[1] for the fast path
    const ushort* e1p = e + 524288 + ((b * 64 + i) * 64 + r) * 64 + c0;
    u32x4 e1r0 = *(const u32x4*)(e1p);
    u32x4 e1r1 = *(const u32x4*)(e1p + 8);
    f4 pe1t[4];
    {
        f4 a, bq, c, d;
        cvt8(e1r0, a, bq); cvt8(e1r1, c, d);
        pe1t[0] = a  * *(const f4*)(table + 64 + c0);
        pe1t[1] = bq * *(const f4*)(table + 64 + c0 + 4);
        pe1t[2] = c  * *(const f4*)(table + 64 + c0 + 8);
        pe1t[3] = d  * *(const f4*)(table + 64 + c0 + 12);
    }

    const ushort* e0base = e + ((b * 64 + j0) * 64 + r) * 64 + c0;           // +4096/j
    const ushort* e2base = e + 1048576 + ((b * 64 + i) * 64 + j0) * 64 + c0; // +64/j
    float* ob = out + (size_t)((b * 64 + i) * 64 + j0) * 4096;

    // prefetch tile 0 e0 (16 bf16 = 32B)
    u32x4 ce0a = *(const u32x4*)(e0base);
    u32x4 ce0b = *(const u32x4*)(e0base + 8);

    __syncthreads();   // Wl ready; the ONLY barrier

    #pragma unroll 1
    for (int jt = 0; jt < 4; ++jt) {
        const int jj = j0 + jt;

        // ---- phase A: build X tile (bf16 -> f32 -> bf16, swizzled) ----
        {
            const ushort* e2p = e2base + jt * 64;
            u32x4 e2a = *(const u32x4*)(e2p);
            u32x4 e2b = *(const u32x4*)(e2p + 8);
            f4 e0f[4], e2f[4];
            cvt8(ce0a, e0f[0], e0f[1]); cvt8(ce0b, e0f[2], e0f[3]);
            cvt8(e2a,  e2f[0], e2f[1]); cvt8(e2b,  e2f[2], e2f[3]);
            f4 xv[4];
            bool slow = (i == jj) || (r == jj) || (r == i);
            if (slow) {
                int p = (i == jj) ? 5 : (jj == r) ? 4 : 3;
                const float* pp = table + p * 64 + c0;
                f4 e1f[4];
                cvt8(e1r0, e1f[0], e1f[1]); cvt8(e1r1, e1f[2], e1f[3]);
                #pragma unroll
                for (int q = 0; q < 4; ++q)
                    xv[q] = e1f[q] * *(const f4*)(pp + 4 * q) * e2f[q] * e0f[q];
            } else {
                #pragma unroll
                for (int q = 0; q < 4; ++q)
                    xv[q] = pe1t[q] * e2f[q] * e0f[q];
            }
            unsigned xw[8];
            #pragma unroll
            for (int q = 0; q < 4; ++q) {
                xw[2 * q]     = cvtpk(xv[q][0], xv[q][1]);
                xw[2 * q + 1] = cvtpk(xv[q][2], xv[q][3]);
            }
            char* rowp = (char*)XH + r * 128;
            const int rx = (r & 7) << 4;
            u32x4 vlo = {xw[0], xw[1], xw[2], xw[3]};
            u32x4 vhi = {xw[4], xw[5], xw[6], xw[7]};
            *(u32x4*)(rowp + ((c0 * 2)      ^ rx)) = vlo;
            *(u32x4*)(rowp + ((c0 * 2 + 16) ^ rx)) = vhi;
        }

        // prefetch next tile's e0 (covered by phases B-D)
        if (jt < 3) {
            const ushort* ne0 = e0base + (jt + 1) * 4096;
            ce0a = *(const u32x4*)(ne0);
            ce0b = *(const u32x4*)(ne0 + 8);
        }

        // ---- phase B: GEMM1 swapped (weights from LDS) ----
        bf8 a0 = *(const bf8*)((const char*)XH + abyte + ((     lg * 16) ^ arx));
        bf8 a1 = *(const bf8*)((const char*)XH + abyte + ((64 + lg * 16) ^ arx));
        #pragma unroll
        for (int nt = 0; nt < 4; ++nt) {
            const char* wb = (const char*)Wl + (nt * 16 + lr) * 128;
            bf8 b0 = *(const bf8*)(wb + ((     lg * 16) ^ arx));
            bf8 b1 = *(const bf8*)(wb + ((64 + lg * 16) ^ arx));
            f32x4 acc = *(const f4*)(bm + nt * 16 + lg * 4);   // bias as C-init
            acc = __builtin_amdgcn_mfma_f32_16x16x32_bf16(b0, a0, acc, 0, 0, 0);
            acc = __builtin_amdgcn_mfma_f32_16x16x32_bf16(b1, a1, acc, 0, 0, 0);
            unsigned pk0 = cvtpk(silu_f(acc[0]), silu_f(acc[1]));
            unsigned pk1 = cvtpk(silu_f(acc[2]), silu_f(acc[3]));
            u32x2 hv = {pk0, pk1};
            *(u32x2*)((char*)XH + 8192 + abyte + ((nt * 32 + lg * 8) ^ arx)) = hv;
        }

        // ---- phase C: GEMM2 swapped + residual -> O-buffer (LDS) ----
        bf8 h0 = *(const bf8*)((const char*)XH + 8192 + abyte + ((     lg * 16) ^ arx));
        bf8 h1 = *(const bf8*)((const char*)XH + 8192 + abyte + ((64 + lg * 16) ^ arx));
        u32x2 rrv[4];                           // hoist residual before overwrite
        #pragma unroll
        for (int nt = 0; nt < 4; ++nt)
            rrv[nt] = *(const u32x2*)((const char*)XH + abyte +
                                      ((nt * 32 + lg * 8) ^ arx));
        #pragma unroll
        for (int nt = 0; nt < 4; ++nt) {
            const char* wb = (const char*)Wl + (64 + nt * 16 + lr) * 128;
            bf8 b0 = *(const bf8*)(wb + ((     lg * 16) ^ arx));
            bf8 b1 = *(const bf8*)(wb + ((64 + lg * 16) ^ arx));
            f32x4 acc = *(const f4*)(bm + 64 + nt * 16 + lg * 4);
            acc = __builtin_amdgcn_mfma_f32_16x16x32_bf16(b0, h0, acc, 0, 0, 0);
            acc = __builtin_amdgcn_mfma_f32_16x16x32_bf16(b1, h1, acc, 0, 0, 0);
            f4 ov;
            ov[0] = silu_f(acc[0]) + __uint_as_float(rrv[nt][0] << 16);
            ov[1] = silu_f(acc[1]) + __uint_as_float(rrv[nt][0] & 0xffff0000u);
            ov[2] = silu_f(acc[2]) + __uint_as_float(rrv[nt][1] << 16);
            ov[3] = silu_f(acc[3]) + __uint_as_float(rrv[nt][1] & 0xffff0000u);
            *(f4*)((char*)XH + obrow + ((nt * 64 + lg * 16) ^ ((lr & 7) << 4))) = ov;
        }

        // ---- phase D: LDS -> global, 4 rows x 256B contiguous per instr ----
        float* obj = ob + (size_t)jt * 4096 + w * 16 * 64;
        #pragma unroll
        for (int v = 0; v < 4; ++v) {
            const int rw = v * 4 + orr;
            const int rbase = ((rw & 8) ? (8192 + w * 2048) : (w * 2048))
                            + (rw & 7) * 256;
            f4 val = *(const f4*)((const char*)XH + rbase +
                     ((os * 16) ^ ((rw & 7) << 4)));
            *(f4*)(obj + rw * 64 + os * 4) = val;
        }
    }
}

extern "C" void kernel_launch(void* const* d_in, const int* in_sizes, int n_in,
                              void* d_out, int out_size, void* d_ws, size_t ws_size,
                              hipStream_t stream) {
    const float* emb1  = (const float*)d_in[0];
    const float* ef    = (const float*)d_in[1];
    const float* Wz    = (const float*)d_in[2];
    const float* bz    = (const float*)d_in[3];
    const float* Wef   = (const float*)d_in[4];
    const float* table = (const float*)d_in[5];
    const float* Wm    = (const float*)d_in[6];
    const float* bm    = (const float*)d_in[7];
    float* out = (float*)d_out;

    float*  zbuf = (float*)d_ws;                   // 24576 f32
    ushort* ebuf = (ushort*)(zbuf + 24576);        // 1572864 bf16
    ushort* WT   = ebuf + 1572864;                 // 8192 bf16
    ushort* WefT = WT + 8192;                      // 12288 bf16

    k_zw  <<<176,  256, 0, stream>>>(emb1, Wz, bz, Wm, Wef, zbuf, WT, WefT);
    k_e   <<<1536, 64,  0, stream>>>(ef, WefT, zbuf, ebuf);
    k_main<<<2048, 256, 0, stream>>>(ebuf, table, WT, bm, out);
}

// Round 21
// 49.272 us; speedup vs baseline: 1.0060x; 1.0060x over previous
//
#include <hip/hip_runtime.h>

typedef __attribute__((ext_vector_type(4))) float f4;
typedef __attribute__((ext_vector_type(8))) short bf8;     // 8 x bf16 bits
typedef __attribute__((ext_vector_type(4))) float f32x4;
typedef __attribute__((ext_vector_type(2))) unsigned int u32x2;
typedef __attribute__((ext_vector_type(4))) unsigned int u32x4;

__device__ __forceinline__ float silu_f(float v) {
    return v * __builtin_amdgcn_rcpf(1.0f + __expf(-v));
}
__device__ __forceinline__ ushort f2bf(float f) {   // RNE f32->bf16 (setup only)
    unsigned u = __float_as_uint(f);
    u += 0x7fff + ((u >> 16) & 1);
    return (ushort)(u >> 16);
}
__device__ __forceinline__ unsigned cvtpk(float lo, float hi) {
    unsigned r;
    asm("v_cvt_pk_bf16_f32 %0, %1, %2" : "=v"(r) : "v"(lo), "v"(hi));
    return r;   // D[15:0]=bf16(lo), D[31:16]=bf16(hi)
}
// 8 bf16 (u32x4) -> two f4
__device__ __forceinline__ void cvt8(u32x4 v, f4& lo, f4& hi) {
    lo[0] = __uint_as_float(v[0] << 16);
    lo[1] = __uint_as_float(v[0] & 0xffff0000u);
    lo[2] = __uint_as_float(v[1] << 16);
    lo[3] = __uint_as_float(v[1] & 0xffff0000u);
    hi[0] = __uint_as_float(v[2] << 16);
    hi[1] = __uint_as_float(v[2] & 0xffff0000u);
    hi[2] = __uint_as_float(v[3] << 16);
    hi[3] = __uint_as_float(v[3] & 0xffff0000u);
}

// fused: blocks 0..95   -> z_l = silu(emb1 @ Wz[l] + bz[l])
//        blocks 96..127 -> WT  [l][n][k] = bf16(Wm[l][k][n])   (k_main weights)
//        blocks 128..175-> WefT[l][n][kk] = bf16(Wef[l][kk][n]) (k_e weights)
extern "C" __global__ void k_zw(const float* __restrict__ emb1,
                                const float* __restrict__ Wz,
                                const float* __restrict__ bz,
                                const float* __restrict__ Wm,
                                const float* __restrict__ Wef,
                                float* __restrict__ z,
                                ushort* __restrict__ WT,
                                ushort* __restrict__ WefT) {
    if (blockIdx.x < 96) {
        int tid = blockIdx.x * 256 + threadIdx.x;   // 24576
        int k = tid & 63;
        int n = (tid >> 6) & 63;
        int b = (tid >> 12) & 1;
        int l = tid >> 13;
        const float* er = emb1 + (b * 64 + n) * 128;
        const float* w  = Wz + l * 8192 + k;
        float acc = bz[l * 64 + k];
        #pragma unroll 8
        for (int c = 0; c < 128; ++c) acc = fmaf(er[c], w[c * 64], acc);
        z[tid] = silu_f(acc);
    } else if (blockIdx.x < 128) {
        int tid = (blockIdx.x - 96) * 256 + threadIdx.x;  // 8192
        int l = tid >> 12, n = (tid >> 6) & 63, k = tid & 63;
        WT[tid] = f2bf(Wm[l * 4096 + k * 64 + n]);
    } else {
        int tid = (blockIdx.x - 128) * 256 + threadIdx.x; // 12288
        int l = tid >> 12, n = (tid >> 6) & 63, k = tid & 63;
        WefT[tid] = f2bf(Wef[l * 4096 + k * 64 + n]);
    }
}

// e'_l = (ef @ Wef[l]) * z-factor via MFMA (R19-validated, unchanged).
extern "C" __global__ void __launch_bounds__(64)
k_e(const float* __restrict__ ef, const ushort* __restrict__ WefT,
    const float* __restrict__ z, ushort* __restrict__ e) {
    __shared__ ushort EF[2048];   // 16 rows x 64 bf16, 128B rows, XOR-swizzled

    const int t   = threadIdx.x;      // 64
    const int blk = blockIdx.x;       // 1536
    const int l    = blk >> 9;
    const int rt16 = blk & 511;
    const int r0g  = rt16 * 16;       // first global ef-row of this wave

    const int rl = t >> 2;
    const int c0 = (t & 3) << 4;
    {
        const float* src = ef + (size_t)(r0g + rl) * 64 + c0;
        unsigned xw[8];
        #pragma unroll
        for (int q = 0; q < 4; ++q) {
            f4 v = *(const f4*)(src + 4 * q);
            xw[2 * q]     = cvtpk(v[0], v[1]);
            xw[2 * q + 1] = cvtpk(v[2], v[3]);
        }
        char* rowp = (char*)EF + rl * 128;
        const int rx = (rl & 7) << 4;
        u32x4 vlo = {xw[0], xw[1], xw[2], xw[3]};
        u32x4 vhi = {xw[4], xw[5], xw[6], xw[7]};
        *(u32x4*)(rowp + ((c0 * 2)      ^ rx)) = vlo;
        *(u32x4*)(rowp + ((c0 * 2 + 16) ^ rx)) = vhi;
    }
    // wave-local LDS: program order + lgkmcnt suffices, no barrier

    const int lr = t & 15, lg = t >> 4;
    const int abyte = lr * 128;
    const int arx   = (lr & 7) << 4;
    bf8 a0 = *(const bf8*)((const char*)EF + abyte + ((     lg * 16) ^ arx));
    bf8 a1 = *(const bf8*)((const char*)EF + abyte + ((64 + lg * 16) ^ arx));

    const int b  = r0g >> 12;
    const int fi = (r0g >> 6) & 63;
    const int se = (r0g & 63) + lr;
    const int mn = (l == 1) ? fi : se;
    const float* zb = z + l * 8192 + b * 4096 + mn * 64;
    ushort* erow = e + (size_t)l * 524288 + (size_t)(r0g + lr) * 64;

    #pragma unroll
    for (int nt = 0; nt < 4; ++nt) {
        const ushort* wp = WefT + l * 4096 + (nt * 16 + lr) * 64 + lg * 8;
        bf8 b0 = *(const bf8*)(wp);
        bf8 b1 = *(const bf8*)(wp + 32);
        f32x4 acc = {0.f, 0.f, 0.f, 0.f};
        acc = __builtin_amdgcn_mfma_f32_16x16x32_bf16(b0, a0, acc, 0, 0, 0);
        acc = __builtin_amdgcn_mfma_f32_16x16x32_bf16(b1, a1, acc, 0, 0, 0);
        const int k0 = nt * 16 + lg * 4;
        f4 zf = *(const f4*)(zb + k0);
        u32x2 pk = {cvtpk(acc[0] * zf[0], acc[1] * zf[1]),
                    cvtpk(acc[2] * zf[2], acc[3] * zf[3])};
        *(u32x2*)(erow + k0) = pk;
    }
}

// R19/R20 k_main with ONE change: j-strip of 8 (grid 1024 = 4 blocks/CU).
// Halves per-block setup (WT staging, e1 load + pe1t fold, barrier) by
// amortizing over 8 tiles. R9's strip-8 test was confounded by table-gather
// + e1-reconvert regressions; this is the clean isolated test.
extern "C" __global__ void __launch_bounds__(256, 4)
k_main(const ushort* __restrict__ e, const float* __restrict__ table,
       const ushort* __restrict__ WT, const float* __restrict__ bm,
       float* __restrict__ out) {
    __shared__ ushort Wl[8192];       // both layers, 128B rows, XOR-swizzled
    __shared__ ushort XH[8192];       // [0,8K): X rows; [8K,16K): H rows.
                                      // O-buffer (f32) overlays wave's own
                                      // X slice (rows 0-7) + H slice (8-15).

    const int t   = threadIdx.x;
    // XCD-chunked, reuse-tight decode (1024 blocks, 8 XCDs; pure bijection):
    // xcd = raw&7 owns semantic chunk of 128; i&7 innermost for e0 reuse.
    const int raw = blockIdx.x;
    const int sem = (raw & 7) * 128 + (raw >> 3);
    const int ig  = sem >> 7;               // 0..7
    const int pos = sem & 127;
    const int b   = pos >> 6;               // 0..1
    const int jq  = (pos >> 3) & 7;         // 0..7
    const int i   = ig * 8 + (pos & 7);     // 0..63
    const int j0  = jq * 8;

    // stage both weight layers swizzled into LDS (once per block)
    #pragma unroll
    for (int p = 0; p < 4; ++p) {
        int g   = p * 256 + t;                  // 1024 x 16B chunks
        int row = g >> 3;                       // 128 rows x 128B
        int cb  = (g & 7) * 16;
        u32x4 v = *(const u32x4*)(WT + g * 8);
        *(u32x4*)((char*)Wl + row * 128 + (cb ^ ((row & 7) << 4))) = v;
    }

    // build-role ids (coalesced: thread covers 16 cols of one row)
    const int r  = t >> 2;
    const int c0 = (t & 3) << 4;
    // frag-role ids
    const int ln = t & 63, w = t >> 6;
    const int lr = ln & 15, lg = ln >> 4;
    const int abyte = (w * 16 + lr) * 128;
    const int arx   = (lr & 7) << 4;
    // output-transpose ids: 4 row-groups x 16 chunks (256B/row per instr)
    const int orr = ln >> 4, os = ln & 15;
    const int obrow = ((lr & 8) ? (8192 + w * 2048) : (w * 2048)) + (lr & 7) * 256;

    // e1 slice: bf16 load once; fold f32*pat[1] for the fast path
    const ushort* e1p = e + 524288 + ((b * 64 + i) * 64 + r) * 64 + c0;
    u32x4 e1r0 = *(const u32x4*)(e1p);
    u32x4 e1r1 = *(const u32x4*)(e1p + 8);
    f4 pe1t[4];
    {
        f4 a, bq, c, d;
        cvt8(e1r0, a, bq); cvt8(e1r1, c, d);
        pe1t[0] = a  * *(const f4*)(table + 64 + c0);
        pe1t[1] = bq * *(const f4*)(table + 64 + c0 + 4);
        pe1t[2] = c  * *(const f4*)(table + 64 + c0 + 8);
        pe1t[3] = d  * *(const f4*)(table + 64 + c0 + 12);
    }

    const ushort* e0base = e + ((b * 64 + j0) * 64 + r) * 64 + c0;           // +4096/j
    const ushort* e2base = e + 1048576 + ((b * 64 + i) * 64 + j0) * 64 + c0; // +64/j
    float* ob = out + (size_t)((b * 64 + i) * 64 + j0) * 4096;

    // prefetch tile 0 e0 (16 bf16 = 32B)
    u32x4 ce0a = *(const u32x4*)(e0base);
    u32x4 ce0b = *(const u32x4*)(e0base + 8);

    __syncthreads();   // Wl ready; the ONLY barrier

    #pragma unroll 1
    for (int jt = 0; jt < 8; ++jt) {
        const int jj = j0 + jt;

        // ---- phase A: build X tile (bf16 -> f32 -> bf16, swizzled) ----
        {
            const ushort* e2p = e2base + jt * 64;
            u32x4 e2a = *(const u32x4*)(e2p);
            u32x4 e2b = *(const u32x4*)(e2p + 8);
            f4 e0f[4], e2f[4];
            cvt8(ce0a, e0f[0], e0f[1]); cvt8(ce0b, e0f[2], e0f[3]);
            cvt8(e2a,  e2f[0], e2f[1]); cvt8(e2b,  e2f[2], e2f[3]);
            f4 xv[4];
            bool slow = (i == jj) || (r == jj) || (r == i);
            if (slow) {
                int p = (i == jj) ? 5 : (jj == r) ? 4 : 3;
                const float* pp = table + p * 64 + c0;
                f4 e1f[4];
                cvt8(e1r0, e1f[0], e1f[1]); cvt8(e1r1, e1f[2], e1f[3]);
                #pragma unroll
                for (int q = 0; q < 4; ++q)
                    xv[q] = e1f[q] * *(const f4*)(pp + 4 * q) * e2f[q] * e0f[q];
            } else {
                #pragma unroll
                for (int q = 0; q < 4; ++q)
                    xv[q] = pe1t[q] * e2f[q] * e0f[q];
            }
            unsigned xw[8];
            #pragma unroll
            for (int q = 0; q < 4; ++q) {
                xw[2 * q]     = cvtpk(xv[q][0], xv[q][1]);
                xw[2 * q + 1] = cvtpk(xv[q][2], xv[q][3]);
            }
            char* rowp = (char*)XH + r * 128;
            const int rx = (r & 7) << 4;
            u32x4 vlo = {xw[0], xw[1], xw[2], xw[3]};
            u32x4 vhi = {xw[4], xw[5], xw[6], xw[7]};
            *(u32x4*)(rowp + ((c0 * 2)      ^ rx)) = vlo;
            *(u32x4*)(rowp + ((c0 * 2 + 16) ^ rx)) = vhi;
        }

        // prefetch next tile's e0 (covered by phases B-D)
        if (jt < 7) {
            const ushort* ne0 = e0base + (jt + 1) * 4096;
            ce0a = *(const u32x4*)(ne0);
            ce0b = *(const u32x4*)(ne0 + 8);
        }

        // ---- phase B: GEMM1 swapped (weights from LDS) ----
        bf8 a0 = *(const bf8*)((const char*)XH + abyte + ((     lg * 16) ^ arx));
        bf8 a1 = *(const bf8*)((const char*)XH + abyte + ((64 + lg * 16) ^ arx));
        #pragma unroll
        for (int nt = 0; nt < 4; ++nt) {
            const char* wb = (const char*)Wl + (nt * 16 + lr) * 128;
            bf8 b0 = *(const bf8*)(wb + ((     lg * 16) ^ arx));
            bf8 b1 = *(const bf8*)(wb + ((64 + lg * 16) ^ arx));
            f32x4 acc = *(const f4*)(bm + nt * 16 + lg * 4);   // bias as C-init
            acc = __builtin_amdgcn_mfma_f32_16x16x32_bf16(b0, a0, acc, 0, 0, 0);
            acc = __builtin_amdgcn_mfma_f32_16x16x32_bf16(b1, a1, acc, 0, 0, 0);
            unsigned pk0 = cvtpk(silu_f(acc[0]), silu_f(acc[1]));
            unsigned pk1 = cvtpk(silu_f(acc[2]), silu_f(acc[3]));
            u32x2 hv = {pk0, pk1};
            *(u32x2*)((char*)XH + 8192 + abyte + ((nt * 32 + lg * 8) ^ arx)) = hv;
        }

        // ---- phase C: GEMM2 swapped + residual -> O-buffer (LDS) ----
        bf8 h0 = *(const bf8*)((const char*)XH + 8192 + abyte + ((     lg * 16) ^ arx));
        bf8 h1 = *(const bf8*)((const char*)XH + 8192 + abyte + ((64 + lg * 16) ^ arx));
        u32x2 rrv[4];                           // hoist residual before overwrite
        #pragma unroll
        for (int nt = 0; nt < 4; ++nt)
            rrv[nt] = *(const u32x2*)((const char*)XH + abyte +
                                      ((nt * 32 + lg * 8) ^ arx));
        #pragma unroll
        for (int nt = 0; nt < 4; ++nt) {
            const char* wb = (const char*)Wl + (64 + nt * 16 + lr) * 128;
            bf8 b0 = *(const bf8*)(wb + ((     lg * 16) ^ arx));
            bf8 b1 = *(const bf8*)(wb + ((64 + lg * 16) ^ arx));
            f32x4 acc = *(const f4*)(bm + 64 + nt * 16 + lg * 4);
            acc = __builtin_amdgcn_mfma_f32_16x16x32_bf16(b0, h0, acc, 0, 0, 0);
            acc = __builtin_amdgcn_mfma_f32_16x16x32_bf16(b1, h1, acc, 0, 0, 0);
            f4 ov;
            ov[0] = silu_f(acc[0]) + __uint_as_float(rrv[nt][0] << 16);
            ov[1] = silu_f(acc[1]) + __uint_as_float(rrv[nt][0] & 0xffff0000u);
            ov[2] = silu_f(acc[2]) + __uint_as_float(rrv[nt][1] << 16);
            ov[3] = silu_f(acc[3]) + __uint_as_float(rrv[nt][1] & 0xffff0000u);
            *(f4*)((char*)XH + obrow + ((nt * 64 + lg * 16) ^ ((lr & 7) << 4))) = ov;
        }

        // ---- phase D: LDS -> global, 4 rows x 256B contiguous per instr ----
        float* obj = ob + (size_t)jt * 4096 + w * 16 * 64;
        #pragma unroll
        for (int v = 0; v < 4; ++v) {
            const int rw = v * 4 + orr;
            const int rbase = ((rw & 8) ? (8192 + w * 2048) : (w * 2048))
                            + (rw & 7) * 256;
            f4 val = *(const f4*)((const char*)XH + rbase +
                     ((os * 16) ^ ((rw & 7) << 4)));
            *(f4*)(obj + rw * 64 + os * 4) = val;
        }
    }
}

extern "C" void kernel_launch(void* const* d_in, const int* in_sizes, int n_in,
                              void* d_out, int out_size, void* d_ws, size_t ws_size,
                              hipStream_t stream) {
    const float* emb1  = (const float*)d_in[0];
    const float* ef    = (const float*)d_in[1];
    const float* Wz    = (const float*)d_in[2];
    const float* bz    = (const float*)d_in[3];
    const float* Wef   = (const float*)d_in[4];
    const float* table = (const float*)d_in[5];
    const float* Wm    = (const float*)d_in[6];
    const float* bm    = (const float*)d_in[7];
    float* out = (float*)d_out;

    float*  zbuf = (float*)d_ws;                   // 24576 f32
    ushort* ebuf = (ushort*)(zbuf + 24576);        // 1572864 bf16
    ushort* WT   = ebuf + 1572864;                 // 8192 bf16
    ushort* WefT = WT + 8192;                      // 12288 bf16

    k_zw  <<<176,  256, 0, stream>>>(emb1, Wz, bz, Wm, Wef, zbuf, WT, WefT);
    k_e   <<<1536, 64,  0, stream>>>(ef, WefT, zbuf, ebuf);
    k_main<<<1024, 256, 0, stream>>>(ebuf, table, WT, bm, out);
}